// Round 6
// baseline (89.592 us; speedup 1.0000x reference)
//
#include <hip/hip_runtime.h>
#include <math.h>

// Problem constants (match reference)
#define B_  4
#define C_  128
#define H_  240
#define W_  320
#define N_  1024
#define NPTS (B_ * N_)          // 4096
#define HW_ (H_ * W_)
#define NBINS 960               // key = b*240 + y0
#define SLAB  30                // rows of y0 per streaming block
#define NSLAB 8                 // 240 / 30
#define LROWS 33                // SLAB + 3 halo rows (y0-1 .. y0+2)
#define LDSF  (LROWS * W_)      // 10560 floats = 42.24 KB
#define NFB   (B_ * C_ * NSLAB) // 4096 streaming blocks

typedef float f4 __attribute__((ext_vector_type(4)));
typedef float f2 __attribute__((ext_vector_type(2)));

__device__ __forceinline__ f4 load4(const float* p) {
    f4 v; __builtin_memcpy(&v, p, 16); return v;
}
__device__ __forceinline__ f2 load2(const float* p) {
    f2 v; __builtin_memcpy(&v, p, 8); return v;
}

// ---------------------------------------------------------------------------
// Kernel 0: counting-sorts.
//   permB/invB/binStart: by (batch, y0 of F_b sample row)  -> streaming pass
//   permA:               by (batch, y0 of F_a sample row)  -> F_a gather pass
// Slot assignment within a bin is atomic-race nondeterministic, but all
// downstream per-point values are pure functions of the point id and all
// final reductions are fixed-order -> output bitwise deterministic.
// ---------------------------------------------------------------------------
__global__ __launch_bounds__(1024) void gn_sort_kernel(
    const float* __restrict__ ma, const float* __restrict__ mb,
    const float* __restrict__ noise,
    int* __restrict__ permA, int* __restrict__ permB,
    int* __restrict__ invB, int* __restrict__ binStart)
{
    __shared__ int hist[NBINS];
    __shared__ int cursor[NBINS];

    // ---- pass 1: key by F_b sample row; also emit invB + binStart ----
    for (int i = threadIdx.x; i < NBINS; i += 1024) hist[i] = 0;
    __syncthreads();
    int keyB[4];
    #pragma unroll
    for (int k = 0; k < 4; ++k) {
        const int p = threadIdx.x + (k << 10);
        const float ys = 2.0f * noise[p * 2 + 1] - 1.0f + mb[p * 2 + 1] * 0.125f;
        const int y0 = min(max((int)floorf(ys), 1), H_ - 3);
        keyB[k] = (p >> 10) * H_ + y0;
        atomicAdd(&hist[keyB[k]], 1);
    }
    __syncthreads();
    if (threadIdx.x < 64) {
        const int lane = threadIdx.x;
        const int base = lane * 15;
        int loc[15]; int s = 0;
        #pragma unroll
        for (int i = 0; i < 15; ++i) { loc[i] = s; s += hist[base + i]; }
        int incl = s;
        #pragma unroll
        for (int off = 1; off < 64; off <<= 1) {
            const int v = __shfl_up(incl, off, 64);
            if (lane >= off) incl += v;
        }
        const int excl = incl - s;
        #pragma unroll
        for (int i = 0; i < 15; ++i) cursor[base + i] = excl + loc[i];
    }
    __syncthreads();
    for (int i = threadIdx.x; i < NBINS; i += 1024) binStart[i] = cursor[i];
    if (threadIdx.x == 0) binStart[NBINS] = NPTS;
    __syncthreads();
    #pragma unroll
    for (int k = 0; k < 4; ++k) {
        const int p = threadIdx.x + (k << 10);
        const int pos = atomicAdd(&cursor[keyB[k]], 1);
        permB[pos] = p;
        invB[p] = pos;
    }
    __syncthreads();

    // ---- pass 2: key by F_a sample row ----
    for (int i = threadIdx.x; i < NBINS; i += 1024) hist[i] = 0;
    __syncthreads();
    int keyA[4];
    #pragma unroll
    for (int k = 0; k < 4; ++k) {
        const int p = threadIdx.x + (k << 10);
        const float ya = ma[p * 2 + 1] * 0.125f;
        const int y0 = min(max((int)floorf(ya), 0), H_ - 2);
        keyA[k] = (p >> 10) * H_ + y0;
        atomicAdd(&hist[keyA[k]], 1);
    }
    __syncthreads();
    if (threadIdx.x < 64) {
        const int lane = threadIdx.x;
        const int base = lane * 15;
        int loc[15]; int s = 0;
        #pragma unroll
        for (int i = 0; i < 15; ++i) { loc[i] = s; s += hist[base + i]; }
        int incl = s;
        #pragma unroll
        for (int off = 1; off < 64; off <<= 1) {
            const int v = __shfl_up(incl, off, 64);
            if (lane >= off) incl += v;
        }
        const int excl = incl - s;
        #pragma unroll
        for (int i = 0; i < 15; ++i) cursor[base + i] = excl + loc[i];
    }
    __syncthreads();
    #pragma unroll
    for (int k = 0; k < 4; ++k) {
        const int p = threadIdx.x + (k << 10);
        permA[atomicAdd(&cursor[keyA[k]], 1)] = p;
    }
}

// ---------------------------------------------------------------------------
// Kernel 1 (fused):
//  blocks [0, NFB):      F_b STREAMING. block = (b, c, slab). Copies 33
//                        contiguous plane rows (42 KB) to LDS at streaming BW,
//                        then computes fs/jx/jy for the ~128 points whose y0
//                        lies in the slab. Writes slot-major -> coalesced.
//  blocks [NFB, +1024):  F_a random gather (R5 structure), writes ws_ft[c][slot].
// ---------------------------------------------------------------------------
__global__ __launch_bounds__(256) void gn_gather_kernel(
    const float* __restrict__ Fa, const float* __restrict__ Fb,
    const float* __restrict__ ma, const float* __restrict__ mb,
    const float* __restrict__ noise,
    const int* __restrict__ permA, const int* __restrict__ permB,
    const int* __restrict__ invB, const int* __restrict__ binStart,
    float* __restrict__ ws_ft, float* __restrict__ fjp)
{
    __shared__ float rows[LDSF];
    const int tid = threadIdx.x;

    if (blockIdx.x < NFB) {
        // ---------------- F_b streaming path ----------------
        const int blk = blockIdx.x;
        const int c  = blk & (C_ - 1);        // channel
        const int bs = blk >> 7;              // (b, slab)
        const int b  = bs >> 3;
        const int s  = bs & (NSLAB - 1);
        const int ybase = s * SLAB - 1;       // first LDS row = image row ybase

        const float* __restrict__ plane = Fb + ((size_t)(b * C_ + c)) * HW_;
        const int srcbase = ybase * W_;

        // linear 42 KB copy, f4-vectorized, bounds-checked at image edges
        for (int i = tid; i < LDSF / 4; i += 256) {
            const int flat = i << 2;
            const int src = srcbase + flat;
            f4 v = {0.f, 0.f, 0.f, 0.f};
            if (src >= 0 && src < HW_) v = load4(plane + src);
            *(f4*)&rows[flat] = v;
        }
        __syncthreads();

        const int binbase = b * H_ + s * SLAB;
        const int pLo = binStart[binbase];
        const int pHi = binStart[binbase + SLAB];

        for (int i = pLo + tid; i < pHi; i += 256) {
            const int p = permB[i];
            const float ubx = mb[p * 2 + 0] * 0.125f;
            const float uby = mb[p * 2 + 1] * 0.125f;
            const float xs  = 2.0f * noise[p * 2 + 0] - 1.0f + ubx;
            const float ys  = 2.0f * noise[p * 2 + 1] - 1.0f + uby;

            const float bx0f = floorf(xs), by0f = floorf(ys);
            const float wx = xs - bx0f, wy = ys - by0f;
            const int x0 = min(max((int)bx0f, 1), W_ - 3);
            const int y0 = min(max((int)by0f, 1), H_ - 3);
            const int rel = y0 - ybase;                  // 1..30

            const float* rY0 = &rows[rel * W_];
            const float* rY1 = rY0 + W_;
            const float* rYm = rY0 - W_;
            const float* rYp = rY1 + W_;

            const float r0m = rY0[x0 - 1], r00 = rY0[x0];
            const float r01 = rY0[x0 + 1], r0p = rY0[x0 + 2];
            const float r1m = rY1[x0 - 1], r10 = rY1[x0];
            const float r11 = rY1[x0 + 1], r1p = rY1[x0 + 2];
            const float rm0 = rYm[x0],     rm1 = rYm[x0 + 1];
            const float rp0 = rYp[x0],     rp1 = rYp[x0 + 1];

            const float w00 = (1.f - wx) * (1.f - wy);
            const float w01 = wx * (1.f - wy);
            const float w10 = (1.f - wx) * wy;
            const float w11 = wx * wy;

            const float fs = r00 * w00 + r01 * w01 + r10 * w10 + r11 * w11;
            const float jx = 0.5f * ((r01 - r0m) * w00 + (r0p - r00) * w01
                                   + (r11 - r1m) * w10 + (r1p - r10) * w11);
            const float jy = 0.5f * ((r10 - rm0) * w00 + (r11 - rm1) * w01
                                   + (rp0 - r00) * w10 + (rp1 - r01) * w11);

            const size_t base = (size_t)c * 3 * NPTS + i;   // slot-major
            fjp[base]            = fs;
            fjp[base + NPTS]     = jx;
            fjp[base + 2 * NPTS] = jy;
        }
    } else {
        // ---------------- F_a random-gather path ----------------
        const int fi   = blockIdx.x - NFB;            // 0..1023
        const int w    = (fi << 2) | (tid >> 6);      // wave 0..4095
        const int lane = tid & 63;
        const int pg   = w >> 6;                      // point group 0..63
        const int c0   = (w & 63) << 1;               // channels c0, c0+1
        const int p    = permA[(pg << 6) | lane];
        const int b    = p >> 10;

        const float xa = ma[p * 2 + 0] * 0.125f;
        const float ya = ma[p * 2 + 1] * 0.125f;
        const float ax0f = floorf(xa), ay0f = floorf(ya);
        const float awx = xa - ax0f, awy = ya - ay0f;
        const int ax0 = min(max((int)ax0f, 0), W_ - 2);
        const int ay0 = min(max((int)ay0f, 0), H_ - 2);
        const int o0 = ay0 * W_ + ax0;
        const int o1 = o0 + W_;

        const float* __restrict__ fa0 = Fa + ((size_t)(b * C_ + c0)) * HW_;
        const float* __restrict__ fa1 = fa0 + HW_;

        const f2 a0_0 = load2(fa0 + o0);
        const f2 a1_0 = load2(fa0 + o1);
        const f2 a0_1 = load2(fa1 + o0);
        const f2 a1_1 = load2(fa1 + o1);

        const float w00 = (1.f - awx) * (1.f - awy);
        const float w01 = awx * (1.f - awy);
        const float w10 = (1.f - awx) * awy;
        const float w11 = awx * awy;

        const float ft0 = a0_0.x * w00 + a0_0.y * w01 + a1_0.x * w10 + a1_0.y * w11;
        const float ft1 = a0_1.x * w00 + a0_1.y * w01 + a1_1.x * w10 + a1_1.y * w11;

        const int slot = invB[p];
        ws_ft[(size_t)c0 * NPTS + slot]       = ft0;   // channel-major
        ws_ft[(size_t)(c0 + 1) * NPTS + slot] = ft1;
    }
}

// ---------------------------------------------------------------------------
// Kernel 2: per-point channel reduction (fixed order c=0..127) + 2x2 GN solve.
// thread = slot; all partial reads fully coalesced. Deterministic.
// ---------------------------------------------------------------------------
__global__ __launch_bounds__(64) void gn_combine_kernel(
    const float* __restrict__ ws_ft, const float* __restrict__ fjp,
    const float* __restrict__ mb, const float* __restrict__ noise,
    const int* __restrict__ permB,
    float* __restrict__ ws_e1, float* __restrict__ ws_ld)
{
    const int i = blockIdx.x * 64 + threadIdx.x;   // slot
    const int p = permB[i];

    float s[9];
    #pragma unroll
    for (int k = 0; k < 9; ++k) s[k] = 0.f;

    #pragma unroll 4
    for (int c = 0; c < C_; ++c) {
        const float ft = ws_ft[(size_t)c * NPTS + i];
        const size_t base = (size_t)c * 3 * NPTS + i;
        const float fs = fjp[base];
        const float jx = fjp[base + NPTS];
        const float jy = fjp[base + 2 * NPTS];
        s[0] += ft * ft;
        s[1] += fs * fs;
        s[2] += jx * fs;
        s[3] += jx * ft;
        s[4] += jy * fs;
        s[5] += jy * ft;
        s[6] += jx * jx;
        s[7] += jx * jy;
        s[8] += jy * jy;
    }

    const float ubx = mb[p * 2 + 0] * 0.125f;
    const float uby = mb[p * 2 + 1] * 0.125f;
    const float xs  = 2.0f * noise[p * 2 + 0] - 1.0f + ubx;
    const float ys  = 2.0f * noise[p * 2 + 1] - 1.0f + uby;

    const float nt = fmaxf(sqrtf(s[0]), 1e-12f);
    const float ns = fmaxf(sqrtf(s[1]), 1e-12f);
    const float b0 = s[2] / ns - s[3] / nt;
    const float b1 = s[4] / ns - s[5] / nt;
    const float H00 = s[6] + 1e-9f;
    const float H01 = s[7];
    const float H11 = s[8] + 1e-9f;
    const float det = H00 * H11 - H01 * H01;
    const float inv = 1.0f / det;
    const float u0 = (H11 * b0 - H01 * b1) * inv;
    const float u1 = (H00 * b1 - H01 * b0) * inv;
    const float d0 = (ubx - xs) + u0;
    const float d1 = (uby - ys) + u1;
    const float quad = d0 * (H00 * d0 + H01 * d1) + d1 * (H01 * d0 + H11 * d1);
    ws_e1[p] = 0.5f * quad;
    ws_ld[p] = logf(det);
}

// ---------------------------------------------------------------------------
// Kernel 3: single-block deterministic reduction of the 4096 partials.
// ---------------------------------------------------------------------------
__global__ __launch_bounds__(256) void gn_reduce_kernel(
    const float* __restrict__ ws_e1, const float* __restrict__ ws_ld,
    float* __restrict__ out)
{
    __shared__ double sm1[256];
    __shared__ double sm2[256];
    double a1 = 0.0, a2 = 0.0;
    for (int i = threadIdx.x; i < NPTS; i += 256) {
        a1 += (double)ws_e1[i];
        a2 += (double)ws_ld[i];
    }
    sm1[threadIdx.x] = a1;
    sm2[threadIdx.x] = a2;
    __syncthreads();
    for (int s = 128; s > 0; s >>= 1) {
        if (threadIdx.x < s) {
            sm1[threadIdx.x] += sm1[threadIdx.x + s];
            sm2[threadIdx.x] += sm2[threadIdx.x + s];
        }
        __syncthreads();
    }
    if (threadIdx.x == 0) {
        const double e1 = sm1[0];
        const double sum_ld = sm2[0];
        const double log2pi = (double)logf(6.283185307179586f);
        const double e2 = (double)NPTS * log2pi - 0.5 * sum_ld;
        const double e = 1.0 * e1 + (2.0 / 7.0) * e2;   // E1_LAMDA=1, E2_LAMDA=2/7
        out[0] = (float)(0.3 * e);                      // GN_LAMDA * e
        out[1] = (float)e1;
        out[2] = (float)e2;
    }
}

extern "C" void kernel_launch(void* const* d_in, const int* in_sizes, int n_in,
                              void* d_out, int out_size, void* d_ws, size_t ws_size,
                              hipStream_t stream) {
    const float* Fa    = (const float*)d_in[0];
    const float* Fb    = (const float*)d_in[1];
    const float* ma    = (const float*)d_in[2];
    const float* mb    = (const float*)d_in[3];
    const float* noise = (const float*)d_in[4];
    float* out = (float*)d_out;

    float* ws_e1    = (float*)d_ws;                 // 4096
    float* ws_ld    = ws_e1 + NPTS;                 // 4096
    int*   permA    = (int*)(ws_ld + NPTS);         // 4096
    int*   permB    = permA + NPTS;                 // 4096
    int*   invB     = permB + NPTS;                 // 4096
    int*   binStart = invB + NPTS;                  // 1024 (961 used)
    float* ws_ft    = (float*)(binStart + 1024);    // 128*4096   (2 MiB)
    float* fjp      = ws_ft + (size_t)C_ * NPTS;    // 128*3*4096 (6 MiB)

    gn_sort_kernel<<<1, 1024, 0, stream>>>(ma, mb, noise, permA, permB,
                                           invB, binStart);
    gn_gather_kernel<<<NFB + 1024, 256, 0, stream>>>(Fa, Fb, ma, mb, noise,
                                                     permA, permB, invB,
                                                     binStart, ws_ft, fjp);
    gn_combine_kernel<<<NPTS / 64, 64, 0, stream>>>(ws_ft, fjp, mb, noise,
                                                    permB, ws_e1, ws_ld);
    gn_reduce_kernel<<<1, 256, 0, stream>>>(ws_e1, ws_ld, out);
}

// Round 7
// 79.192 us; speedup vs baseline: 1.1313x; 1.1313x over previous
//
#include <hip/hip_runtime.h>
#include <math.h>

// Problem constants (match reference)
#define B_  4
#define C_  128
#define H_  240
#define W_  320
#define N_  1024
#define NPTS (B_ * N_)          // 4096
#define HW_ (H_ * W_)
#define NBINS 960               // key = b*240 + y0
#define SLAB  30                // rows of y0 per streaming block
#define NSLAB 8                 // 240 / 30
#define LROWS 33                // SLAB + 3 halo rows (y0-1 .. y0+2)
#define LDSF  (LROWS * W_)      // 10560 floats = 42.24 KB
#define NF4   (LDSF / 4)        // 2640 f4 slots
#define NFB   (B_ * C_ * NSLAB) // 4096 streaming blocks
#define NTOT  (NFB + 1024)      // 5120 blocks total (every 5th is F_a)

typedef float f4 __attribute__((ext_vector_type(4)));
typedef float f2 __attribute__((ext_vector_type(2)));

__device__ __forceinline__ f4 load4(const float* p) {
    f4 v; __builtin_memcpy(&v, p, 16); return v;
}
__device__ __forceinline__ f2 load2(const float* p) {
    f2 v; __builtin_memcpy(&v, p, 8); return v;
}

// ---------------------------------------------------------------------------
// Kernel 0: counting-sorts (unchanged from R6).
// ---------------------------------------------------------------------------
__global__ __launch_bounds__(1024) void gn_sort_kernel(
    const float* __restrict__ ma, const float* __restrict__ mb,
    const float* __restrict__ noise,
    int* __restrict__ permA, int* __restrict__ permB,
    int* __restrict__ invB, int* __restrict__ binStart)
{
    __shared__ int hist[NBINS];
    __shared__ int cursor[NBINS];

    // ---- pass 1: key by F_b sample row; also emit invB + binStart ----
    for (int i = threadIdx.x; i < NBINS; i += 1024) hist[i] = 0;
    __syncthreads();
    int keyB[4];
    #pragma unroll
    for (int k = 0; k < 4; ++k) {
        const int p = threadIdx.x + (k << 10);
        const float ys = 2.0f * noise[p * 2 + 1] - 1.0f + mb[p * 2 + 1] * 0.125f;
        const int y0 = min(max((int)floorf(ys), 1), H_ - 3);
        keyB[k] = (p >> 10) * H_ + y0;
        atomicAdd(&hist[keyB[k]], 1);
    }
    __syncthreads();
    if (threadIdx.x < 64) {
        const int lane = threadIdx.x;
        const int base = lane * 15;
        int loc[15]; int s = 0;
        #pragma unroll
        for (int i = 0; i < 15; ++i) { loc[i] = s; s += hist[base + i]; }
        int incl = s;
        #pragma unroll
        for (int off = 1; off < 64; off <<= 1) {
            const int v = __shfl_up(incl, off, 64);
            if (lane >= off) incl += v;
        }
        const int excl = incl - s;
        #pragma unroll
        for (int i = 0; i < 15; ++i) cursor[base + i] = excl + loc[i];
    }
    __syncthreads();
    for (int i = threadIdx.x; i < NBINS; i += 1024) binStart[i] = cursor[i];
    if (threadIdx.x == 0) binStart[NBINS] = NPTS;
    __syncthreads();
    #pragma unroll
    for (int k = 0; k < 4; ++k) {
        const int p = threadIdx.x + (k << 10);
        const int pos = atomicAdd(&cursor[keyB[k]], 1);
        permB[pos] = p;
        invB[p] = pos;
    }
    __syncthreads();

    // ---- pass 2: key by F_a sample row ----
    for (int i = threadIdx.x; i < NBINS; i += 1024) hist[i] = 0;
    __syncthreads();
    int keyA[4];
    #pragma unroll
    for (int k = 0; k < 4; ++k) {
        const int p = threadIdx.x + (k << 10);
        const float ya = ma[p * 2 + 1] * 0.125f;
        const int y0 = min(max((int)floorf(ya), 0), H_ - 2);
        keyA[k] = (p >> 10) * H_ + y0;
        atomicAdd(&hist[keyA[k]], 1);
    }
    __syncthreads();
    if (threadIdx.x < 64) {
        const int lane = threadIdx.x;
        const int base = lane * 15;
        int loc[15]; int s = 0;
        #pragma unroll
        for (int i = 0; i < 15; ++i) { loc[i] = s; s += hist[base + i]; }
        int incl = s;
        #pragma unroll
        for (int off = 1; off < 64; off <<= 1) {
            const int v = __shfl_up(incl, off, 64);
            if (lane >= off) incl += v;
        }
        const int excl = incl - s;
        #pragma unroll
        for (int i = 0; i < 15; ++i) cursor[base + i] = excl + loc[i];
    }
    __syncthreads();
    #pragma unroll
    for (int k = 0; k < 4; ++k) {
        const int p = threadIdx.x + (k << 10);
        permA[atomicAdd(&cursor[keyA[k]], 1)] = p;
    }
}

// ---------------------------------------------------------------------------
// Kernel 1 (fused, interleaved):
//  bid % 5 == 4 -> F_a random gather (fa_idx = bid/5, 1024 blocks)
//  else         -> F_b streaming     (s_idx = bid - bid/5, 4096 blocks)
// Streaming copy is reg-staged + fully unrolled: 11 independent dwordx4
// loads issued back-to-back, ONE waitcnt, then 11 ds_write_b128.
// ---------------------------------------------------------------------------
__global__ __launch_bounds__(256) void gn_gather_kernel(
    const float* __restrict__ Fa, const float* __restrict__ Fb,
    const float* __restrict__ ma, const float* __restrict__ mb,
    const float* __restrict__ noise,
    const int* __restrict__ permA, const int* __restrict__ permB,
    const int* __restrict__ invB, const int* __restrict__ binStart,
    float* __restrict__ ws_ft, float* __restrict__ fjp)
{
    __shared__ float rows[LDSF];
    const int tid = threadIdx.x;
    const int bid = blockIdx.x;

    if ((bid % 5) != 4) {
        // ---------------- F_b streaming path ----------------
        const int blk = bid - bid / 5;        // 0..4095
        const int c  = blk & (C_ - 1);        // channel
        const int bs = blk >> 7;              // (b, slab)
        const int b  = bs >> 3;
        const int s  = bs & (NSLAB - 1);
        const int ybase = s * SLAB - 1;       // first LDS row = image row ybase

        const float* __restrict__ plane = Fb + ((size_t)(b * C_ + c)) * HW_;
        const int srcbase = ybase * W_;

        // ---- pipelined 42 KB copy: 11 loads -> 1 wait -> 11 LDS writes ----
        f4 tmp[11];
        #pragma unroll
        for (int k = 0; k < 11; ++k) {
            const int slot = tid + (k << 8);            // f4 index
            int src = srcbase + (slot << 2);
            src = min(max(src, 0), HW_ - 4);            // clamp (halo rows unused)
            tmp[k] = load4(plane + src);                // redundant for slot>=NF4, harmless
        }
        #pragma unroll
        for (int k = 0; k < 11; ++k) {
            const int slot = tid + (k << 8);
            if (slot < NF4) *(f4*)&rows[slot << 2] = tmp[k];
        }
        __syncthreads();

        const int binbase = b * H_ + s * SLAB;
        const int pLo = binStart[binbase];
        const int pHi = binStart[binbase + SLAB];

        for (int i = pLo + tid; i < pHi; i += 256) {
            const int p = permB[i];
            const float ubx = mb[p * 2 + 0] * 0.125f;
            const float uby = mb[p * 2 + 1] * 0.125f;
            const float xs  = 2.0f * noise[p * 2 + 0] - 1.0f + ubx;
            const float ys  = 2.0f * noise[p * 2 + 1] - 1.0f + uby;

            const float bx0f = floorf(xs), by0f = floorf(ys);
            const float wx = xs - bx0f, wy = ys - by0f;
            const int x0 = min(max((int)bx0f, 1), W_ - 3);
            const int y0 = min(max((int)by0f, 1), H_ - 3);
            const int rel = y0 - ybase;                  // 1..30

            const float* rY0 = &rows[rel * W_];
            const float* rY1 = rY0 + W_;
            const float* rYm = rY0 - W_;
            const float* rYp = rY1 + W_;

            const float r0m = rY0[x0 - 1], r00 = rY0[x0];
            const float r01 = rY0[x0 + 1], r0p = rY0[x0 + 2];
            const float r1m = rY1[x0 - 1], r10 = rY1[x0];
            const float r11 = rY1[x0 + 1], r1p = rY1[x0 + 2];
            const float rm0 = rYm[x0],     rm1 = rYm[x0 + 1];
            const float rp0 = rYp[x0],     rp1 = rYp[x0 + 1];

            const float w00 = (1.f - wx) * (1.f - wy);
            const float w01 = wx * (1.f - wy);
            const float w10 = (1.f - wx) * wy;
            const float w11 = wx * wy;

            const float fs = r00 * w00 + r01 * w01 + r10 * w10 + r11 * w11;
            const float jx = 0.5f * ((r01 - r0m) * w00 + (r0p - r00) * w01
                                   + (r11 - r1m) * w10 + (r1p - r10) * w11);
            const float jy = 0.5f * ((r10 - rm0) * w00 + (r11 - rm1) * w01
                                   + (rp0 - r00) * w10 + (rp1 - r01) * w11);

            const size_t base = (size_t)c * 3 * NPTS + i;   // slot-major
            fjp[base]            = fs;
            fjp[base + NPTS]     = jx;
            fjp[base + 2 * NPTS] = jy;
        }
    } else {
        // ---------------- F_a random-gather path ----------------
        const int fi   = bid / 5;                     // 0..1023
        const int w    = (fi << 2) | (tid >> 6);      // wave 0..4095
        const int lane = tid & 63;
        const int pg   = w >> 6;                      // point group 0..63
        const int c0   = (w & 63) << 1;               // channels c0, c0+1
        const int p    = permA[(pg << 6) | lane];
        const int b    = p >> 10;

        const float xa = ma[p * 2 + 0] * 0.125f;
        const float ya = ma[p * 2 + 1] * 0.125f;
        const float ax0f = floorf(xa), ay0f = floorf(ya);
        const float awx = xa - ax0f, awy = ya - ay0f;
        const int ax0 = min(max((int)ax0f, 0), W_ - 2);
        const int ay0 = min(max((int)ay0f, 0), H_ - 2);
        const int o0 = ay0 * W_ + ax0;
        const int o1 = o0 + W_;

        const float* __restrict__ fa0 = Fa + ((size_t)(b * C_ + c0)) * HW_;
        const float* __restrict__ fa1 = fa0 + HW_;

        const f2 a0_0 = load2(fa0 + o0);
        const f2 a1_0 = load2(fa0 + o1);
        const f2 a0_1 = load2(fa1 + o0);
        const f2 a1_1 = load2(fa1 + o1);

        const float w00 = (1.f - awx) * (1.f - awy);
        const float w01 = awx * (1.f - awy);
        const float w10 = (1.f - awx) * awy;
        const float w11 = awx * awy;

        const float ft0 = a0_0.x * w00 + a0_0.y * w01 + a1_0.x * w10 + a1_0.y * w11;
        const float ft1 = a0_1.x * w00 + a0_1.y * w01 + a1_1.x * w10 + a1_1.y * w11;

        const int slot = invB[p];
        ws_ft[(size_t)c0 * NPTS + slot]       = ft0;   // channel-major
        ws_ft[(size_t)(c0 + 1) * NPTS + slot] = ft1;
    }
}

// ---------------------------------------------------------------------------
// Kernel 2: per-point channel reduction (fixed order c=0..127) + 2x2 GN solve.
// thread = slot; all partial reads fully coalesced. Deterministic.
// ---------------------------------------------------------------------------
__global__ __launch_bounds__(64) void gn_combine_kernel(
    const float* __restrict__ ws_ft, const float* __restrict__ fjp,
    const float* __restrict__ mb, const float* __restrict__ noise,
    const int* __restrict__ permB,
    float* __restrict__ ws_e1, float* __restrict__ ws_ld)
{
    const int i = blockIdx.x * 64 + threadIdx.x;   // slot
    const int p = permB[i];

    float s[9];
    #pragma unroll
    for (int k = 0; k < 9; ++k) s[k] = 0.f;

    #pragma unroll 4
    for (int c = 0; c < C_; ++c) {
        const float ft = ws_ft[(size_t)c * NPTS + i];
        const size_t base = (size_t)c * 3 * NPTS + i;
        const float fs = fjp[base];
        const float jx = fjp[base + NPTS];
        const float jy = fjp[base + 2 * NPTS];
        s[0] += ft * ft;
        s[1] += fs * fs;
        s[2] += jx * fs;
        s[3] += jx * ft;
        s[4] += jy * fs;
        s[5] += jy * ft;
        s[6] += jx * jx;
        s[7] += jx * jy;
        s[8] += jy * jy;
    }

    const float ubx = mb[p * 2 + 0] * 0.125f;
    const float uby = mb[p * 2 + 1] * 0.125f;
    const float xs  = 2.0f * noise[p * 2 + 0] - 1.0f + ubx;
    const float ys  = 2.0f * noise[p * 2 + 1] - 1.0f + uby;

    const float nt = fmaxf(sqrtf(s[0]), 1e-12f);
    const float ns = fmaxf(sqrtf(s[1]), 1e-12f);
    const float b0 = s[2] / ns - s[3] / nt;
    const float b1 = s[4] / ns - s[5] / nt;
    const float H00 = s[6] + 1e-9f;
    const float H01 = s[7];
    const float H11 = s[8] + 1e-9f;
    const float det = H00 * H11 - H01 * H01;
    const float inv = 1.0f / det;
    const float u0 = (H11 * b0 - H01 * b1) * inv;
    const float u1 = (H00 * b1 - H01 * b0) * inv;
    const float d0 = (ubx - xs) + u0;
    const float d1 = (uby - ys) + u1;
    const float quad = d0 * (H00 * d0 + H01 * d1) + d1 * (H01 * d0 + H11 * d1);
    ws_e1[p] = 0.5f * quad;
    ws_ld[p] = logf(det);
}

// ---------------------------------------------------------------------------
// Kernel 3: single-block deterministic reduction of the 4096 partials.
// ---------------------------------------------------------------------------
__global__ __launch_bounds__(256) void gn_reduce_kernel(
    const float* __restrict__ ws_e1, const float* __restrict__ ws_ld,
    float* __restrict__ out)
{
    __shared__ double sm1[256];
    __shared__ double sm2[256];
    double a1 = 0.0, a2 = 0.0;
    for (int i = threadIdx.x; i < NPTS; i += 256) {
        a1 += (double)ws_e1[i];
        a2 += (double)ws_ld[i];
    }
    sm1[threadIdx.x] = a1;
    sm2[threadIdx.x] = a2;
    __syncthreads();
    for (int s = 128; s > 0; s >>= 1) {
        if (threadIdx.x < s) {
            sm1[threadIdx.x] += sm1[threadIdx.x + s];
            sm2[threadIdx.x] += sm2[threadIdx.x + s];
        }
        __syncthreads();
    }
    if (threadIdx.x == 0) {
        const double e1 = sm1[0];
        const double sum_ld = sm2[0];
        const double log2pi = (double)logf(6.283185307179586f);
        const double e2 = (double)NPTS * log2pi - 0.5 * sum_ld;
        const double e = 1.0 * e1 + (2.0 / 7.0) * e2;   // E1_LAMDA=1, E2_LAMDA=2/7
        out[0] = (float)(0.3 * e);                      // GN_LAMDA * e
        out[1] = (float)e1;
        out[2] = (float)e2;
    }
}

extern "C" void kernel_launch(void* const* d_in, const int* in_sizes, int n_in,
                              void* d_out, int out_size, void* d_ws, size_t ws_size,
                              hipStream_t stream) {
    const float* Fa    = (const float*)d_in[0];
    const float* Fb    = (const float*)d_in[1];
    const float* ma    = (const float*)d_in[2];
    const float* mb    = (const float*)d_in[3];
    const float* noise = (const float*)d_in[4];
    float* out = (float*)d_out;

    float* ws_e1    = (float*)d_ws;                 // 4096
    float* ws_ld    = ws_e1 + NPTS;                 // 4096
    int*   permA    = (int*)(ws_ld + NPTS);         // 4096
    int*   permB    = permA + NPTS;                 // 4096
    int*   invB     = permB + NPTS;                 // 4096
    int*   binStart = invB + NPTS;                  // 1024 (961 used)
    float* ws_ft    = (float*)(binStart + 1024);    // 128*4096   (2 MiB)
    float* fjp      = ws_ft + (size_t)C_ * NPTS;    // 128*3*4096 (6 MiB)

    gn_sort_kernel<<<1, 1024, 0, stream>>>(ma, mb, noise, permA, permB,
                                           invB, binStart);
    gn_gather_kernel<<<NTOT, 256, 0, stream>>>(Fa, Fb, ma, mb, noise,
                                               permA, permB, invB,
                                               binStart, ws_ft, fjp);
    gn_combine_kernel<<<NPTS / 64, 64, 0, stream>>>(ws_ft, fjp, mb, noise,
                                                    permB, ws_e1, ws_ld);
    gn_reduce_kernel<<<1, 256, 0, stream>>>(ws_e1, ws_ld, out);
}